// Round 4
// baseline (1642.870 us; speedup 1.0000x reference)
//
#include <hip/hip_runtime.h>
#include <cstddef>

// Problem constants (from reference)
#define BATCH 128
#define DIN   2048
#define NN    2048
#define TT    50
#define MM    (BATCH * TT)   // 6400, m = b*50 + t
#define BN_EPS 1e-4

typedef double double4_t __attribute__((ext_vector_type(4)));

// ---------------------------------------------------------------------------
// MFMA f64 layout probe. Correctness-neutral; encodes its verdict in DURATION
// (s_memrealtime ticks, ~100 MHz => 1 tick = 10 ns):
//   +0    us : H1  row=4*(lane/16)+reg, col=lane%16   (standard mapping works)
//   +350  us : H2  row=(lane/16)+4*reg, col=lane%16
//   +700  us : H3  transposed H1 (row=lane%16, col=4*(lane/16)+reg)
//   +1050 us : H4  transposed H2
//   +1400 us : no hypothesis matched (A/B k-pairing or operand roles differ)
//   +2100 us : __builtin_amdgcn_mfma_f64_16x16x4f64 unavailable on target
// All pattern values are small integers: every product/sum is exact in fp64,
// so exact == comparison is valid. Pattern is asymmetric (G9).
// ---------------------------------------------------------------------------
__global__ void mfma_probe_kernel(double* scratch) {
    const int lane = threadIdx.x & 63;
#if __has_builtin(__builtin_amdgcn_mfma_f64_16x16x4f64)
    __shared__ double At[16][4];
    __shared__ double Bt[4][16];
    {
        const int m = lane & 15, k = lane >> 4;
        At[m][k] = (double)((m * 7 + k * 13) % 31 - 15);
        Bt[k][m] = (double)((k * 11 + m * 3) % 29 - 14);
    }
    __syncthreads();
    const int m = lane & 15, g = lane >> 4;
    double a = At[m][g];            // assumed A: m=lane%16, k=lane/16
    double b = Bt[g][m];            // assumed B: n=lane%16, k=lane/16
    double4_t d = {0.0, 0.0, 0.0, 0.0};
    d = __builtin_amdgcn_mfma_f64_16x16x4f64(a, b, d, 0, 0, 0);

    int okmask = 15;
#pragma unroll
    for (int r = 0; r < 4; ++r) {
        double h0 = 0.0, h1 = 0.0, h2 = 0.0, h3 = 0.0;
#pragma unroll
        for (int k = 0; k < 4; ++k) {
            h0 += At[4 * g + r][k] * Bt[k][m];
            h1 += At[g + 4 * r][k] * Bt[k][m];
            h2 += At[m][k] * Bt[k][4 * g + r];
            h3 += At[m][k] * Bt[k][g + 4 * r];
        }
        if (d[r] != h0) okmask &= ~1;
        if (d[r] != h1) okmask &= ~2;
        if (d[r] != h2) okmask &= ~4;
        if (d[r] != h3) okmask &= ~8;
    }
    int code = 0;
    if      (__all(okmask & 1)) code = 1;
    else if (__all(okmask & 2)) code = 2;
    else if (__all(okmask & 4)) code = 3;
    else if (__all(okmask & 8)) code = 4;

    // defeat DCE
#pragma unroll
    for (int r = 0; r < 4; ++r) scratch[lane * 4 + r] = d[r];
    scratch[256 + lane] = (double)code;

    unsigned long long delay =
        (code == 1) ? 0ull :
        (code == 2) ? 35000ull :
        (code == 3) ? 70000ull :
        (code == 4) ? 105000ull : 140000ull;
    unsigned long long t0 = __builtin_amdgcn_s_memrealtime();
    while (__builtin_amdgcn_s_memrealtime() - t0 < delay) {}
#else
    scratch[lane] = -1.0;
    unsigned long long t0 = __builtin_amdgcn_s_memrealtime();
    while (__builtin_amdgcn_s_memrealtime() - t0 < 210000ull) {}
#endif
}

// ---------------------------------------------------------------------------
// VALU fp64 GEMM (verified-exact path): PSP[m][n] = sum_d X[b,d,t]*W[n,d].
// 128x64 tile, BK=16, 256 threads, 8x4 fp64 acc/thread.
// fp64 LDS: convert fp32->fp64 ONCE at staging (round 2 spent ~1/3 of VALU
// issue on in-loop v_cvt_f64_f32; this removes it).
// ---------------------------------------------------------------------------
#define TM 128
#define TN 64
#define TK 16
#define ASTR 130   // doubles; 130*8=1040 B rows keep 16B alignment
#define BSTR 66    // 66*8=528 B

template <typename PT>
__global__ __launch_bounds__(256) void gemm_psp_kernel(
    const float* __restrict__ X,     // [B][DIN][T]
    const float* __restrict__ W,     // [N][DIN]
    PT* __restrict__ PSP)            // [M][N]
{
    __shared__ double As[TK][ASTR];
    __shared__ double Bs[TK][BSTR];

    const int tid = threadIdx.x;
    const int m0 = blockIdx.y * TM;  // 50 blocks
    const int n0 = blockIdx.x * TN;  // 32 blocks

    // A staging: 128m x 16k, 8 elements/thread, coalesced in t
    const int a_m = tid & 127;
    const int a_k = tid >> 7;                 // 0..1
    const int m_g = m0 + a_m;
    const int ab  = m_g / TT;
    const int at  = m_g - ab * TT;
    const float* Aptr = X + (size_t)ab * (DIN * TT) + at;   // + k*TT

    // B staging: 16k x 64n, float4 along k
    const int b_n = tid >> 2;                 // 0..63
    const int b_k = (tid & 3) * 4;            // 0,4,8,12
    const float* Wptr = W + (size_t)(n0 + b_n) * DIN + b_k;

    const int ty = tid >> 4;   // 0..15 -> rows ty*8..+7
    const int tx = tid & 15;   // 0..15 -> cols tx*4..+3

    double acc[8][4];
#pragma unroll
    for (int i = 0; i < 8; ++i)
#pragma unroll
        for (int j = 0; j < 4; ++j) acc[i][j] = 0.0;

    for (int k0 = 0; k0 < DIN; k0 += TK) {
#pragma unroll
        for (int j = 0; j < 8; ++j) {
            const int kr = a_k + 2 * j;
            As[kr][a_m] = (double)Aptr[(k0 + kr) * TT];
        }
        float4 w4 = *(const float4*)(Wptr + k0);
        Bs[b_k + 0][b_n] = (double)w4.x;
        Bs[b_k + 1][b_n] = (double)w4.y;
        Bs[b_k + 2][b_n] = (double)w4.z;
        Bs[b_k + 3][b_n] = (double)w4.w;
        __syncthreads();

#pragma unroll
        for (int k = 0; k < TK; ++k) {
            double2 a2[4], b2[2];
            a2[0] = *(const double2*)&As[k][ty * 8 + 0];
            a2[1] = *(const double2*)&As[k][ty * 8 + 2];
            a2[2] = *(const double2*)&As[k][ty * 8 + 4];
            a2[3] = *(const double2*)&As[k][ty * 8 + 6];
            b2[0] = *(const double2*)&Bs[k][tx * 4 + 0];
            b2[1] = *(const double2*)&Bs[k][tx * 4 + 2];
            const double* av = (const double*)a2;
            const double* bv = (const double*)b2;
#pragma unroll
            for (int i = 0; i < 8; ++i)
#pragma unroll
                for (int j = 0; j < 4; ++j)
                    acc[i][j] = fma(av[i], bv[j], acc[i][j]);
        }
        __syncthreads();
    }

#pragma unroll
    for (int i = 0; i < 8; ++i) {
        const int mrow = m0 + ty * 8 + i;
        PT* row = PSP + (size_t)mrow * NN + n0 + tx * 4;
#pragma unroll
        for (int j = 0; j < 4; ++j) row[j] = (PT)acc[i][j];
    }
}

// ---------------------------------------------------------------------------
// BN stats per (t,n): two-pass mean / inv-std over batch, all fp64.
// ---------------------------------------------------------------------------
template <typename PT>
__global__ __launch_bounds__(256) void stats_kernel(
    const PT* __restrict__ PSP,       // [M][N], m=b*50+t
    const float* __restrict__ bias,   // [N]
    double* __restrict__ mean_out,    // [T][N]
    double* __restrict__ invstd_out)  // [T][N]
{
    const int t = blockIdx.x >> 3;
    const int n = ((blockIdx.x & 7) << 8) + threadIdx.x;
    const double bb = (double)bias[n];
    const PT* p = PSP + (size_t)t * NN + n;     // + b*(50*2048)

    double s = 0.0;
#pragma unroll 8
    for (int b = 0; b < BATCH; ++b) s += (double)p[(size_t)b * (TT * NN)];
    const double mean = s * (1.0 / BATCH) + bb;

    double ss = 0.0;
#pragma unroll 8
    for (int b = 0; b < BATCH; ++b) {
        double d = ((double)p[(size_t)b * (TT * NN)] + bb) - mean;
        ss += d * d;
    }
    const double var = ss * (1.0 / BATCH);
    mean_out[t * NN + n]   = mean;
    invstd_out[t * NN + n] = 1.0 / sqrt(var + BN_EPS);
}

// ---------------------------------------------------------------------------
// LIF recurrence (fp64 state) + coalesced spike writeout via LDS transpose.
// ---------------------------------------------------------------------------
template <typename PT>
__global__ __launch_bounds__(256) void recur_kernel(
    const PT* __restrict__ PSP,           // [M][N]
    const float* __restrict__ bias,       // [N]
    const double* __restrict__ mean_arr,  // [T][N]
    const double* __restrict__ invstd_arr,// [T][N]
    const float* __restrict__ gamma,      // [T][N]
    const float* __restrict__ decay_v,    // [N]
    const float* __restrict__ reset_decay,// [N]
    const float* __restrict__ reset_v,    // [N]
    float* __restrict__ out)              // spikes [B][N][T] ++ final_v ++ final_reset
{
    __shared__ float spk[256 * (TT + 1)];

    const int b  = blockIdx.x >> 3;
    const int nc = blockIdx.x & 7;
    const int n  = (nc << 8) + threadIdx.x;
    const int tid = threadIdx.x;

    const double dv = (double)decay_v[n];
    const double rd = (double)reset_decay[n];
    const double rv = (double)reset_v[n];
    const double bb = (double)bias[n];

    double v = 0.0, r = 0.0;
    const PT* p = PSP + (size_t)b * (TT * NN) + n;   // + t*NN
    const float* ga = gamma + n;
    const double* me = mean_arr + n;
    const double* is = invstd_arr + n;

    for (int t = 0; t < TT; ++t) {
        const double psp = (double)p[t * NN] + bb;
        const double bn  = (double)ga[t * NN] * (psp - me[t * NN]) * is[t * NN];
        v = v * dv + bn - r;
        const double s = (v > 1.0) ? 1.0 : 0.0;
        r = r * rd + s * rv;
        spk[tid * (TT + 1) + t] = (float)s;
    }
    __syncthreads();

    const size_t base = (size_t)b * (NN * TT) + (size_t)nc * (256 * TT);
    for (int i = tid; i < 256 * TT; i += 256) {
        const int n_l = i / TT;
        const int t   = i - n_l * TT;
        out[base + i] = spk[n_l * (TT + 1) + t];
    }

    const size_t fin = (size_t)BATCH * NN * TT;
    out[fin + (size_t)b * NN + n]                      = (float)v;
    out[fin + (size_t)BATCH * NN + (size_t)b * NN + n] = (float)r;
}

// ---------------------------------------------------------------------------
template <typename PT>
static void launch_all(const float* X, const float* W, const float* bias,
                       const float* gamma, const float* decay_v,
                       const float* reset_dec, const float* reset_v,
                       float* out, void* d_ws, hipStream_t stream)
{
    PT* PSP = (PT*)d_ws;
    char* after = (char*)d_ws + (size_t)MM * NN * sizeof(PT);
    double* meanA  = (double*)after;
    double* invstd = meanA + (size_t)TT * NN;

    // probe scratch = start of PSP region (overwritten by the GEMM right after)
    mfma_probe_kernel<<<1, 64, 0, stream>>>((double*)d_ws);

    dim3 ggrid(NN / TN, MM / TM);   // (32, 50)
    gemm_psp_kernel<PT><<<ggrid, 256, 0, stream>>>(X, W, PSP);
    stats_kernel<PT><<<TT * (NN / 256), 256, 0, stream>>>(PSP, bias, meanA, invstd);
    recur_kernel<PT><<<BATCH * (NN / 256), 256, 0, stream>>>(
        PSP, bias, meanA, invstd, gamma, decay_v, reset_dec, reset_v, out);
}

extern "C" void kernel_launch(void* const* d_in, const int* in_sizes, int n_in,
                              void* d_out, int out_size, void* d_ws, size_t ws_size,
                              hipStream_t stream) {
    (void)in_sizes; (void)n_in; (void)out_size;
    const float* X          = (const float*)d_in[0];  // [B, DIN, T]
    const float* W          = (const float*)d_in[1];  // [N, DIN]
    const float* bias       = (const float*)d_in[2];  // [N]
    const float* gamma      = (const float*)d_in[3];  // [T, N]
    const float* decay_v    = (const float*)d_in[4];  // [N]
    const float* reset_dec  = (const float*)d_in[5];  // [N]
    const float* reset_v    = (const float*)d_in[6];  // [N]
    float* out = (float*)d_out;

    const size_t need_d = (size_t)MM * NN * 8 + (size_t)TT * NN * 16;
    if (ws_size >= need_d)
        launch_all<double>(X, W, bias, gamma, decay_v, reset_dec, reset_v, out, d_ws, stream);
    else
        launch_all<float>(X, W, bias, gamma, decay_v, reset_dec, reset_v, out, d_ws, stream);
}

// Round 5
// 1073.557 us; speedup vs baseline: 1.5303x; 1.5303x over previous
//
#include <hip/hip_runtime.h>
#include <cstddef>

// Problem constants (from reference)
#define BATCH 128
#define DIN   2048
#define NN    2048
#define TT    50
#define MM    (BATCH * TT)   // 6400, m = b*50 + t
#define BN_EPS 1e-4

typedef double double4_t __attribute__((ext_vector_type(4)));

// ---------------------------------------------------------------------------
// fp64-MFMA GEMM: PSP[m][n] = sum_d X[b,d,t] * W[n,d], m = b*50+t.
// 64x64 block tile, 4 waves 2x2, each wave 32x32 via 2x2 v_mfma_f64_16x16x4.
// Fragment layouts verified ON HARDWARE by the round-4 probe (timing-channel
// verdict = H2):
//   A: m = lane&15, k = lane>>4
//   B: n = lane&15, k = lane>>4
//   D: row = (lane>>4) + 4*reg, col = lane&15   <-- f64 differs from the
//       row=4*(lane>>4)+reg mapping of all other gfx950 MFMA shapes!
// fp32 staged in LDS (stride 72 -> exactly 2 lanes/bank on every access,
// free per m136), cvt to f64 in regs. fp64 exactness is required: spikes are
// a hard Heaviside at v>1.0 (fp32 GEMM flips spikes and fails).
// ---------------------------------------------------------------------------
#define LDS_STRIDE 72

template <typename PT>
__global__ __launch_bounds__(256) void gemm_psp_kernel(
    const float* __restrict__ X,     // [B][DIN][T]
    const float* __restrict__ W,     // [N][DIN]
    PT* __restrict__ PSP)            // [M][N]
{
    __shared__ float As[16][LDS_STRIDE];
    __shared__ float Bs[16][LDS_STRIDE];

    const int tid = threadIdx.x;
    const int m0 = blockIdx.y * 64;  // 100 blocks
    const int n0 = blockIdx.x * 64;  // 32 blocks

    // --- staging indices ---
    // A tile (16k x 64m): 4 rows per thread, lanes over m (coalesced in t)
    const int a_m = tid & 63;
    const int a_k = tid >> 6;                 // 0..3
    const int m_g = m0 + a_m;
    const int ab  = m_g / TT;
    const int at  = m_g - ab * TT;
    const float* Aptr = X + (size_t)ab * (DIN * TT) + at;   // + k*TT

    // B tile (16k x 64n): float4 along k of W[N][K]
    const int b_n = tid >> 2;                 // 0..63
    const int b_k = (tid & 3) * 4;            // 0,4,8,12
    const float* Wptr = W + (size_t)(n0 + b_n) * DIN + b_k;

    // --- MFMA indices ---
    const int lane = tid & 63;
    const int wv   = tid >> 6;                // wave 0..3
    const int wm   = (wv >> 1) * 32;          // 0 / 32
    const int wn   = (wv & 1) * 32;
    const int row  = lane & 15;               // A m-index / B n-index
    const int grp  = lane >> 4;               // 0..3 = k within quad

    double4_t acc[2][2];
#pragma unroll
    for (int i = 0; i < 2; ++i)
#pragma unroll
        for (int j = 0; j < 2; ++j) acc[i][j] = double4_t{0.0, 0.0, 0.0, 0.0};

    for (int k0 = 0; k0 < DIN; k0 += 16) {
        // stage A (16x64): bank = (8*kr + a_m) % 32 -> 2 lanes/bank, free
#pragma unroll
        for (int j = 0; j < 4; ++j) {
            const int kr = a_k + 4 * j;
            As[kr][a_m] = Aptr[(k0 + kr) * TT];
        }
        // stage B (16x64)
        float4 w4 = *(const float4*)(Wptr + k0);
        Bs[b_k + 0][b_n] = w4.x;
        Bs[b_k + 1][b_n] = w4.y;
        Bs[b_k + 2][b_n] = w4.z;
        Bs[b_k + 3][b_n] = w4.w;
        __syncthreads();

#pragma unroll
        for (int kq = 0; kq < 16; kq += 4) {
            const int kr = kq + grp;
            const double a0 = (double)As[kr][wm + row];
            const double a1 = (double)As[kr][wm + row + 16];
            const double b0 = (double)Bs[kr][wn + row];
            const double b1 = (double)Bs[kr][wn + row + 16];
            acc[0][0] = __builtin_amdgcn_mfma_f64_16x16x4f64(a0, b0, acc[0][0], 0, 0, 0);
            acc[0][1] = __builtin_amdgcn_mfma_f64_16x16x4f64(a0, b1, acc[0][1], 0, 0, 0);
            acc[1][0] = __builtin_amdgcn_mfma_f64_16x16x4f64(a1, b0, acc[1][0], 0, 0, 0);
            acc[1][1] = __builtin_amdgcn_mfma_f64_16x16x4f64(a1, b1, acc[1][1], 0, 0, 0);
        }
        __syncthreads();
    }

    // D layout (HW-verified H2): row = grp + 4*reg, col = lane&15
#pragma unroll
    for (int i = 0; i < 2; ++i)
#pragma unroll
        for (int j = 0; j < 2; ++j) {
#pragma unroll
            for (int r = 0; r < 4; ++r) {
                const int mrow = m0 + wm + 16 * i + grp + 4 * r;
                PSP[(size_t)mrow * NN + (n0 + wn + 16 * j + row)] = (PT)acc[i][j][r];
            }
        }
}

// ---------------------------------------------------------------------------
// BN stats per (t,n): two-pass mean / inv-std over batch, all fp64.
// ---------------------------------------------------------------------------
template <typename PT>
__global__ __launch_bounds__(256) void stats_kernel(
    const PT* __restrict__ PSP,       // [M][N], m=b*50+t
    const float* __restrict__ bias,   // [N]
    double* __restrict__ mean_out,    // [T][N]
    double* __restrict__ invstd_out)  // [T][N]
{
    const int t = blockIdx.x >> 3;
    const int n = ((blockIdx.x & 7) << 8) + threadIdx.x;
    const double bb = (double)bias[n];
    const PT* p = PSP + (size_t)t * NN + n;     // + b*(50*2048)

    double s = 0.0;
#pragma unroll 8
    for (int b = 0; b < BATCH; ++b) s += (double)p[(size_t)b * (TT * NN)];
    const double mean = s * (1.0 / BATCH) + bb;

    double ss = 0.0;
#pragma unroll 8
    for (int b = 0; b < BATCH; ++b) {
        double d = ((double)p[(size_t)b * (TT * NN)] + bb) - mean;
        ss += d * d;
    }
    const double var = ss * (1.0 / BATCH);
    mean_out[t * NN + n]   = mean;
    invstd_out[t * NN + n] = 1.0 / sqrt(var + BN_EPS);
}

// ---------------------------------------------------------------------------
// LIF recurrence (fp64 state) + coalesced spike writeout via LDS transpose.
// ---------------------------------------------------------------------------
template <typename PT>
__global__ __launch_bounds__(256) void recur_kernel(
    const PT* __restrict__ PSP,           // [M][N]
    const float* __restrict__ bias,       // [N]
    const double* __restrict__ mean_arr,  // [T][N]
    const double* __restrict__ invstd_arr,// [T][N]
    const float* __restrict__ gamma,      // [T][N]
    const float* __restrict__ decay_v,    // [N]
    const float* __restrict__ reset_decay,// [N]
    const float* __restrict__ reset_v,    // [N]
    float* __restrict__ out)              // spikes [B][N][T] ++ final_v ++ final_reset
{
    __shared__ float spk[256 * (TT + 1)];

    const int b  = blockIdx.x >> 3;
    const int nc = blockIdx.x & 7;
    const int n  = (nc << 8) + threadIdx.x;
    const int tid = threadIdx.x;

    const double dv = (double)decay_v[n];
    const double rd = (double)reset_decay[n];
    const double rv = (double)reset_v[n];
    const double bb = (double)bias[n];

    double v = 0.0, r = 0.0;
    const PT* p = PSP + (size_t)b * (TT * NN) + n;   // + t*NN
    const float* ga = gamma + n;
    const double* me = mean_arr + n;
    const double* is = invstd_arr + n;

    for (int t = 0; t < TT; ++t) {
        const double psp = (double)p[t * NN] + bb;
        const double bn  = (double)ga[t * NN] * (psp - me[t * NN]) * is[t * NN];
        v = v * dv + bn - r;
        const double s = (v > 1.0) ? 1.0 : 0.0;
        r = r * rd + s * rv;
        spk[tid * (TT + 1) + t] = (float)s;
    }
    __syncthreads();

    const size_t base = (size_t)b * (NN * TT) + (size_t)nc * (256 * TT);
    for (int i = tid; i < 256 * TT; i += 256) {
        const int n_l = i / TT;
        const int t   = i - n_l * TT;
        out[base + i] = spk[n_l * (TT + 1) + t];
    }

    const size_t fin = (size_t)BATCH * NN * TT;
    out[fin + (size_t)b * NN + n]                      = (float)v;
    out[fin + (size_t)BATCH * NN + (size_t)b * NN + n] = (float)r;
}

// ---------------------------------------------------------------------------
template <typename PT>
static void launch_all(const float* X, const float* W, const float* bias,
                       const float* gamma, const float* decay_v,
                       const float* reset_dec, const float* reset_v,
                       float* out, void* d_ws, hipStream_t stream)
{
    PT* PSP = (PT*)d_ws;
    char* after = (char*)d_ws + (size_t)MM * NN * sizeof(PT);
    double* meanA  = (double*)after;
    double* invstd = meanA + (size_t)TT * NN;

    dim3 ggrid(NN / 64, MM / 64);   // (32, 100)
    gemm_psp_kernel<PT><<<ggrid, 256, 0, stream>>>(X, W, PSP);
    stats_kernel<PT><<<TT * (NN / 256), 256, 0, stream>>>(PSP, bias, meanA, invstd);
    recur_kernel<PT><<<BATCH * (NN / 256), 256, 0, stream>>>(
        PSP, bias, meanA, invstd, gamma, decay_v, reset_dec, reset_v, out);
}

extern "C" void kernel_launch(void* const* d_in, const int* in_sizes, int n_in,
                              void* d_out, int out_size, void* d_ws, size_t ws_size,
                              hipStream_t stream) {
    (void)in_sizes; (void)n_in; (void)out_size;
    const float* X          = (const float*)d_in[0];  // [B, DIN, T]
    const float* W          = (const float*)d_in[1];  // [N, DIN]
    const float* bias       = (const float*)d_in[2];  // [N]
    const float* gamma      = (const float*)d_in[3];  // [T, N]
    const float* decay_v    = (const float*)d_in[4];  // [N]
    const float* reset_dec  = (const float*)d_in[5];  // [N]
    const float* reset_v    = (const float*)d_in[6];  // [N]
    float* out = (float*)d_out;

    const size_t need_d = (size_t)MM * NN * 8 + (size_t)TT * NN * 16;
    if (ws_size >= need_d)
        launch_all<double>(X, W, bias, gamma, decay_v, reset_dec, reset_v, out, d_ws, stream);
    else
        launch_all<float>(X, W, bias, gamma, decay_v, reset_dec, reset_v, out, d_ws, stream);
}

// Round 6
// 1062.300 us; speedup vs baseline: 1.5465x; 1.0106x over previous
//
#include <hip/hip_runtime.h>
#include <cstddef>

// Problem constants (from reference)
#define BATCH 128
#define DIN   2048
#define NN    2048
#define TT    50
#define MM    (BATCH * TT)   // 6400, m = b*50 + t
#define BN_EPS 1e-4

typedef double double4_t __attribute__((ext_vector_type(4)));

// ---------------------------------------------------------------------------
// fp64-MFMA GEMM v2: PSP[m][n] = sum_d X[b,d,t] * W[n,d], m = b*50+t.
// 64x64 block tile, 4 waves 2x2, each wave 32x32 via 2x2 v_mfma_f64_16x16x4.
// BK=32, register prefetch + LDS double-buffer, ONE barrier per k-iter:
// global loads for iter k+1 fly under iter k's 32-MFMA (2048 cy) window.
// Fragment layouts HW-verified (round-4 probe, verdict H2):
//   A: m = lane&15, k = lane>>4
//   B: n = lane&15, k = lane>>4
//   D: row = (lane>>4) + 4*reg, col = lane&15   (f64 differs from other dtypes!)
// LDS: A as [k][m] stride 72 (2 lanes/bank both phases); B as [n][k] stride 36
// (float4 ds_write_b128 stores; reads (4n+kr)%32 -> 2 lanes/bank). Round-5's
// B-store layout was 4-way conflicted (288 % 32 == 0) -> 9.2e7 conflict cycles.
// fp64 exactness is required: spikes are a hard Heaviside at v>1.0.
// ---------------------------------------------------------------------------
#define BKK 32

template <typename PT>
__global__ __launch_bounds__(256) void gemm_psp_kernel(
    const float* __restrict__ X,     // [B][DIN][T]
    const float* __restrict__ W,     // [N][DIN]
    PT* __restrict__ PSP)            // [M][N]
{
    __shared__ float As[2][BKK][72];   // [buf][k][m]
    __shared__ float Bs[2][64][36];    // [buf][n][k]

    const int tid = threadIdx.x;
    const int m0 = blockIdx.y * 64;  // 100 blocks
    const int n0 = blockIdx.x * 64;  // 32 blocks

    // --- A staging: 64m x 32k, 8 elems/thread, lanes over m (coalesced in t)
    const int a_m = tid & 63;
    const int a_k = tid >> 6;                 // 0..3; rows a_k + 4*j
    const int m_g = m0 + a_m;
    const int ab  = m_g / TT;
    const int at  = m_g - ab * TT;
    const float* Aptr = X + (size_t)ab * (DIN * TT) + at;   // + k*TT

    // --- B staging: 64n x 32k, 8 elems/thread as two float4 along k
    const int b_n = tid >> 2;                 // 0..63
    const int b_k = (tid & 3) * 8;            // 0,8,16,24
    const float* Wptr = W + (size_t)(n0 + b_n) * DIN + b_k;

    // --- MFMA indices ---
    const int lane = tid & 63;
    const int wv   = tid >> 6;                // wave 0..3
    const int wm   = (wv >> 1) * 32;          // 0 / 32
    const int wn   = (wv & 1) * 32;
    const int row  = lane & 15;               // A m-index / B n-index
    const int grp  = lane >> 4;               // 0..3 = k within quad

    double4_t acc[2][2];
#pragma unroll
    for (int i = 0; i < 2; ++i)
#pragma unroll
        for (int j = 0; j < 2; ++j) acc[i][j] = double4_t{0.0, 0.0, 0.0, 0.0};

    // ---- prologue: stage iter 0 into LDS[0]
    {
#pragma unroll
        for (int j = 0; j < 8; ++j)
            As[0][a_k + 4 * j][a_m] = Aptr[(a_k + 4 * j) * TT];
        float4 w0 = *(const float4*)(Wptr);
        float4 w1 = *(const float4*)(Wptr + 4);
        *(float4*)&Bs[0][b_n][b_k]     = w0;
        *(float4*)&Bs[0][b_n][b_k + 4] = w1;
    }

    const int NIT = DIN / BKK;   // 64
    for (int it = 0; it < NIT; ++it) {
        const int buf = it & 1;
        __syncthreads();   // LDS[buf] ready; LDS[1-buf] free (reads done pre-barrier)

        // prefetch iter it+1 into registers (latency hidden under MFMAs below)
        float a_nxt[8];
        float4 b_nxt0, b_nxt1;
        if (it + 1 < NIT) {
            const int k0n = (it + 1) * BKK;
#pragma unroll
            for (int j = 0; j < 8; ++j)
                a_nxt[j] = Aptr[(k0n + a_k + 4 * j) * TT];
            b_nxt0 = *(const float4*)(Wptr + k0n);
            b_nxt1 = *(const float4*)(Wptr + k0n + 4);
        }

        // compute: 8 k-quads x 4 MFMA
#pragma unroll
        for (int kq = 0; kq < BKK; kq += 4) {
            const int kr = kq + grp;
            const double a0 = (double)As[buf][kr][wm + row];
            const double a1 = (double)As[buf][kr][wm + row + 16];
            const double b0 = (double)Bs[buf][wn + row][kr];
            const double b1 = (double)Bs[buf][wn + row + 16][kr];
            acc[0][0] = __builtin_amdgcn_mfma_f64_16x16x4f64(a0, b0, acc[0][0], 0, 0, 0);
            acc[0][1] = __builtin_amdgcn_mfma_f64_16x16x4f64(a0, b1, acc[0][1], 0, 0, 0);
            acc[1][0] = __builtin_amdgcn_mfma_f64_16x16x4f64(a1, b0, acc[1][0], 0, 0, 0);
            acc[1][1] = __builtin_amdgcn_mfma_f64_16x16x4f64(a1, b1, acc[1][1], 0, 0, 0);
        }

        // store prefetched tile into the other buffer (no barrier needed before:
        // all waves' reads of LDS[1-buf] completed before this iter's barrier)
        if (it + 1 < NIT) {
            const int nb = 1 - buf;
#pragma unroll
            for (int j = 0; j < 8; ++j)
                As[nb][a_k + 4 * j][a_m] = a_nxt[j];
            *(float4*)&Bs[nb][b_n][b_k]     = b_nxt0;
            *(float4*)&Bs[nb][b_n][b_k + 4] = b_nxt1;
        }
    }

    // D layout (HW-verified H2): row = grp + 4*reg, col = lane&15
#pragma unroll
    for (int i = 0; i < 2; ++i)
#pragma unroll
        for (int j = 0; j < 2; ++j) {
#pragma unroll
            for (int r = 0; r < 4; ++r) {
                const int mrow = m0 + wm + 16 * i + grp + 4 * r;
                PSP[(size_t)mrow * NN + (n0 + wn + 16 * j + row)] = (PT)acc[i][j][r];
            }
        }
}

// ---------------------------------------------------------------------------
// BN stats per (t,n): two-pass mean / inv-std over batch, all fp64.
// ---------------------------------------------------------------------------
template <typename PT>
__global__ __launch_bounds__(256) void stats_kernel(
    const PT* __restrict__ PSP,       // [M][N], m=b*50+t
    const float* __restrict__ bias,   // [N]
    double* __restrict__ mean_out,    // [T][N]
    double* __restrict__ invstd_out)  // [T][N]
{
    const int t = blockIdx.x >> 3;
    const int n = ((blockIdx.x & 7) << 8) + threadIdx.x;
    const double bb = (double)bias[n];
    const PT* p = PSP + (size_t)t * NN + n;     // + b*(50*2048)

    double s = 0.0;
#pragma unroll 8
    for (int b = 0; b < BATCH; ++b) s += (double)p[(size_t)b * (TT * NN)];
    const double mean = s * (1.0 / BATCH) + bb;

    double ss = 0.0;
#pragma unroll 8
    for (int b = 0; b < BATCH; ++b) {
        double d = ((double)p[(size_t)b * (TT * NN)] + bb) - mean;
        ss += d * d;
    }
    const double var = ss * (1.0 / BATCH);
    mean_out[t * NN + n]   = mean;
    invstd_out[t * NN + n] = 1.0 / sqrt(var + BN_EPS);
}

// ---------------------------------------------------------------------------
// LIF recurrence (fp64 state) + coalesced spike writeout via LDS transpose.
// ---------------------------------------------------------------------------
template <typename PT>
__global__ __launch_bounds__(256) void recur_kernel(
    const PT* __restrict__ PSP,           // [M][N]
    const float* __restrict__ bias,       // [N]
    const double* __restrict__ mean_arr,  // [T][N]
    const double* __restrict__ invstd_arr,// [T][N]
    const float* __restrict__ gamma,      // [T][N]
    const float* __restrict__ decay_v,    // [N]
    const float* __restrict__ reset_decay,// [N]
    const float* __restrict__ reset_v,    // [N]
    float* __restrict__ out)              // spikes [B][N][T] ++ final_v ++ final_reset
{
    __shared__ float spk[256 * (TT + 1)];

    const int b  = blockIdx.x >> 3;
    const int nc = blockIdx.x & 7;
    const int n  = (nc << 8) + threadIdx.x;
    const int tid = threadIdx.x;

    const double dv = (double)decay_v[n];
    const double rd = (double)reset_decay[n];
    const double rv = (double)reset_v[n];
    const double bb = (double)bias[n];

    double v = 0.0, r = 0.0;
    const PT* p = PSP + (size_t)b * (TT * NN) + n;   // + t*NN
    const float* ga = gamma + n;
    const double* me = mean_arr + n;
    const double* is = invstd_arr + n;

    for (int t = 0; t < TT; ++t) {
        const double psp = (double)p[t * NN] + bb;
        const double bn  = (double)ga[t * NN] * (psp - me[t * NN]) * is[t * NN];
        v = v * dv + bn - r;
        const double s = (v > 1.0) ? 1.0 : 0.0;
        r = r * rd + s * rv;
        spk[tid * (TT + 1) + t] = (float)s;
    }
    __syncthreads();

    const size_t base = (size_t)b * (NN * TT) + (size_t)nc * (256 * TT);
    for (int i = tid; i < 256 * TT; i += 256) {
        const int n_l = i / TT;
        const int t   = i - n_l * TT;
        out[base + i] = spk[n_l * (TT + 1) + t];
    }

    const size_t fin = (size_t)BATCH * NN * TT;
    out[fin + (size_t)b * NN + n]                      = (float)v;
    out[fin + (size_t)BATCH * NN + (size_t)b * NN + n] = (float)r;
}

// ---------------------------------------------------------------------------
template <typename PT>
static void launch_all(const float* X, const float* W, const float* bias,
                       const float* gamma, const float* decay_v,
                       const float* reset_dec, const float* reset_v,
                       float* out, void* d_ws, hipStream_t stream)
{
    PT* PSP = (PT*)d_ws;
    char* after = (char*)d_ws + (size_t)MM * NN * sizeof(PT);
    double* meanA  = (double*)after;
    double* invstd = meanA + (size_t)TT * NN;

    dim3 ggrid(NN / 64, MM / 64);   // (32, 100)
    gemm_psp_kernel<PT><<<ggrid, 256, 0, stream>>>(X, W, PSP);
    stats_kernel<PT><<<TT * (NN / 256), 256, 0, stream>>>(PSP, bias, meanA, invstd);
    recur_kernel<PT><<<BATCH * (NN / 256), 256, 0, stream>>>(
        PSP, bias, meanA, invstd, gamma, decay_v, reset_dec, reset_v, out);
}

extern "C" void kernel_launch(void* const* d_in, const int* in_sizes, int n_in,
                              void* d_out, int out_size, void* d_ws, size_t ws_size,
                              hipStream_t stream) {
    (void)in_sizes; (void)n_in; (void)out_size;
    const float* X          = (const float*)d_in[0];  // [B, DIN, T]
    const float* W          = (const float*)d_in[1];  // [N, DIN]
    const float* bias       = (const float*)d_in[2];  // [N]
    const float* gamma      = (const float*)d_in[3];  // [T, N]
    const float* decay_v    = (const float*)d_in[4];  // [N]
    const float* reset_dec  = (const float*)d_in[5];  // [N]
    const float* reset_v    = (const float*)d_in[6];  // [N]
    float* out = (float*)d_out;

    const size_t need_d = (size_t)MM * NN * 8 + (size_t)TT * NN * 16;
    if (ws_size >= need_d)
        launch_all<double>(X, W, bias, gamma, decay_v, reset_dec, reset_v, out, d_ws, stream);
    else
        launch_all<float>(X, W, bias, gamma, decay_v, reset_dec, reset_v, out, d_ws, stream);
}

// Round 8
// 1039.485 us; speedup vs baseline: 1.5805x; 1.0219x over previous
//
#include <hip/hip_runtime.h>
#include <cstddef>

// Problem constants (from reference)
#define BATCH 128
#define DIN   2048
#define NN    2048
#define TT    50
#define MM    (BATCH * TT)   // 6400, m = b*50 + t
#define BN_EPS 1e-4

typedef double double4_t __attribute__((ext_vector_type(4)));
typedef int    int4v    __attribute__((ext_vector_type(4)));

// XOR bank swizzle: keeps float4 alignment (operand is a multiple of 4)
#define SWZ(x) (((x) & 7) << 2)

// ---------------------------------------------------------------------------
// i8-MFMA layout probe (correctness-neutral; verdict in DURATION, 10ns ticks):
//   +0   us : D standard (row=4*(lane>>4)+r, col=lane&15), A/B pack k=(lane>>4)*16+j
//   +200 us : D f64-style (row=(lane>>4)+4*r)
//   +400 us : neither hypothesis matched
//   +600 us : builtin unavailable
// ---------------------------------------------------------------------------
__global__ void i8_probe_kernel(double* scratch) {
    const int lane = threadIdx.x & 63;
#if __has_builtin(__builtin_amdgcn_mfma_i32_16x16x64_i8)
    __shared__ signed char At[16][64];
    __shared__ signed char Bt[64][16];
    for (int j = 0; j < 16; ++j) {
        const int idx = lane * 16 + j;        // 0..1023
        const int m = idx >> 6, k = idx & 63;
        At[m][k] = (signed char)((3 * m + 5 * k) % 17 - 8);
        Bt[k][m] = (signed char)((7 * k + 11 * m) % 19 - 9);
    }
    __syncthreads();
    const int mm = lane & 15, g = lane >> 4;
    union { int4v v; signed char c[16]; } av, bv;
    for (int j = 0; j < 16; ++j) {
        av.c[j] = At[mm][g * 16 + j];
        bv.c[j] = Bt[g * 16 + j][mm];
    }
    int4v d = {0, 0, 0, 0};
    d = __builtin_amdgcn_mfma_i32_16x16x64_i8(av.v, bv.v, d, 0, 0, 0);

    int ok1 = 1, ok2 = 1;
    for (int r = 0; r < 4; ++r) {
        int ref1 = 0, ref2 = 0;
        const int row1 = 4 * g + r, row2 = g + 4 * r;
        for (int k = 0; k < 64; ++k) {
            ref1 += (int)At[row1][k] * (int)Bt[k][mm];
            ref2 += (int)At[row2][k] * (int)Bt[k][mm];
        }
        if (d[r] != ref1) ok1 = 0;
        if (d[r] != ref2) ok2 = 0;
    }
    int code = __all(ok1) ? 1 : (__all(ok2) ? 2 : 0);
    for (int r = 0; r < 4; ++r) scratch[lane * 4 + r] = (double)d[r];
    scratch[256 + lane] = (double)code;
    unsigned long long delay = (code == 1) ? 0ull : (code == 2) ? 20000ull : 40000ull;
    unsigned long long t0 = __builtin_amdgcn_s_memrealtime();
    while (__builtin_amdgcn_s_memrealtime() - t0 < delay) {}
#else
    scratch[lane] = -1.0;
    unsigned long long t0 = __builtin_amdgcn_s_memrealtime();
    while (__builtin_amdgcn_s_memrealtime() - t0 < 60000ull) {}
#endif
}

// ---------------------------------------------------------------------------
// fp64-MFMA GEMM v4: PSP[m][n] = sum_d X[b,d,t]*W[n,d], m = b*50+t.
// EXACT round-6 pipeline (double-buffer BK=32, register prefetch, ONE barrier
// per iter — proven correct at 1008 us), with the LDS squeezed to exactly
// 32768 B -> 5 blocks/CU (round 6 had 36864 B -> 4). Stride-64/32 arrays with
// XOR bank-swizzle (idx ^ ((other&7)<<2)) keep every access at 2 lanes/bank.
// (Round 7's failure was an OOB stride-40 A array, not the occupancy idea.)
// HW-verified fragment layouts (round-4 probe, verdict H2):
//   A: m=lane&15, k=lane>>4 | B: n=lane&15, k=lane>>4
//   D: row=(lane>>4)+4*reg, col=lane&15   (f64-specific!)
// fp64 exactness required: spikes are a hard Heaviside at v>1.0.
// ---------------------------------------------------------------------------
#define BKK 32

template <typename PT>
__global__ __launch_bounds__(256, 5) void gemm_psp_kernel(
    const float* __restrict__ X,     // [B][DIN][T]
    const float* __restrict__ W,     // [N][DIN]
    PT* __restrict__ PSP)            // [M][N]
{
    __shared__ float As[2][BKK][64];   // [buf][k][m^SWZ(k)]
    __shared__ float Bs[2][64][BKK];   // [buf][n][k^SWZ(n)]

    const int tid = threadIdx.x;
    const int m0 = blockIdx.y * 64;  // 100 blocks
    const int n0 = blockIdx.x * 64;  // 32 blocks

    // A staging: 64m x 32k, 8 elems/thread, lanes over m (coalesced in t)
    const int a_m = tid & 63;
    const int a_k = tid >> 6;                 // 0..3; rows a_k + 4*j, j=0..7
    const int m_g = m0 + a_m;
    const int ab  = m_g / TT;
    const int at  = m_g - ab * TT;
    const float* Aptr = X + (size_t)ab * (DIN * TT) + at;   // + k*TT

    // B staging: 64n x 32k, 8 elems/thread as two float4 along k
    const int b_n = tid >> 2;                 // 0..63
    const int b_k = (tid & 3) * 8;            // 0,8,16,24
    const float* Wptr = W + (size_t)(n0 + b_n) * DIN + b_k;
    const int bswz_st = SWZ(b_n);

    // MFMA indices
    const int lane = tid & 63;
    const int wv   = tid >> 6;
    const int wm   = (wv >> 1) * 32;
    const int wn   = (wv & 1) * 32;
    const int row  = lane & 15;
    const int grp  = lane >> 4;
    const int bswz_rd = SWZ(row);    // (wn+row)&7 == (wn+row+16)&7 == row&7

    double4_t acc[2][2];
#pragma unroll
    for (int i = 0; i < 2; ++i)
#pragma unroll
        for (int j = 0; j < 2; ++j) acc[i][j] = double4_t{0.0, 0.0, 0.0, 0.0};

    // prologue: stage iter 0 into buffer 0
    {
#pragma unroll
        for (int j = 0; j < 8; ++j) {
            const int kr = a_k + 4 * j;
            As[0][kr][a_m ^ SWZ(kr)] = Aptr[kr * TT];
        }
        *(float4*)&Bs[0][b_n][(b_k + 0) ^ bswz_st] = *(const float4*)(Wptr);
        *(float4*)&Bs[0][b_n][(b_k + 4) ^ bswz_st] = *(const float4*)(Wptr + 4);
    }

    const int NIT = DIN / BKK;   // 64
    for (int it = 0; it < NIT; ++it) {
        const int buf = it & 1;
        __syncthreads();   // LDS[buf] ready; LDS[1-buf] free

        // register-prefetch iter it+1 (flies under the 32 MFMAs below)
        float a_nxt[8];
        float4 b_nxt0, b_nxt1;
        if (it + 1 < NIT) {
            const int k0n = (it + 1) * BKK;
#pragma unroll
            for (int j = 0; j < 8; ++j)
                a_nxt[j] = Aptr[(k0n + a_k + 4 * j) * TT];
            b_nxt0 = *(const float4*)(Wptr + k0n);
            b_nxt1 = *(const float4*)(Wptr + k0n + 4);
        }

        // compute: 8 k-quads x 4 MFMA
#pragma unroll
        for (int kq = 0; kq < BKK; kq += 4) {
            const int kr = kq + grp;
            const int aswz = SWZ(kr);
            const double a0 = (double)As[buf][kr][(wm + row) ^ aswz];
            const double a1 = (double)As[buf][kr][(wm + row + 16) ^ aswz];
            const double b0 = (double)Bs[buf][wn + row][kr ^ bswz_rd];
            const double b1 = (double)Bs[buf][wn + row + 16][kr ^ bswz_rd];
            acc[0][0] = __builtin_amdgcn_mfma_f64_16x16x4f64(a0, b0, acc[0][0], 0, 0, 0);
            acc[0][1] = __builtin_amdgcn_mfma_f64_16x16x4f64(a0, b1, acc[0][1], 0, 0, 0);
            acc[1][0] = __builtin_amdgcn_mfma_f64_16x16x4f64(a1, b0, acc[1][0], 0, 0, 0);
            acc[1][1] = __builtin_amdgcn_mfma_f64_16x16x4f64(a1, b1, acc[1][1], 0, 0, 0);
        }

        // store prefetched tile into the other buffer
        if (it + 1 < NIT) {
            const int nb = 1 - buf;
#pragma unroll
            for (int j = 0; j < 8; ++j) {
                const int kr = a_k + 4 * j;
                As[nb][kr][a_m ^ SWZ(kr)] = a_nxt[j];
            }
            *(float4*)&Bs[nb][b_n][(b_k + 0) ^ bswz_st] = b_nxt0;
            *(float4*)&Bs[nb][b_n][(b_k + 4) ^ bswz_st] = b_nxt1;
        }
    }

    // D layout (HW-verified H2): row = grp + 4*reg, col = lane&15
#pragma unroll
    for (int i = 0; i < 2; ++i)
#pragma unroll
        for (int j = 0; j < 2; ++j) {
#pragma unroll
            for (int r = 0; r < 4; ++r) {
                const int mrow = m0 + wm + 16 * i + grp + 4 * r;
                PSP[(size_t)mrow * NN + (n0 + wn + 16 * j + row)] = (PT)acc[i][j][r];
            }
        }
}

// ---------------------------------------------------------------------------
// BN stats per (t,n): two-pass mean / inv-std over batch, all fp64.
// ---------------------------------------------------------------------------
template <typename PT>
__global__ __launch_bounds__(256) void stats_kernel(
    const PT* __restrict__ PSP,       // [M][N], m=b*50+t
    const float* __restrict__ bias,   // [N]
    double* __restrict__ mean_out,    // [T][N]
    double* __restrict__ invstd_out)  // [T][N]
{
    const int t = blockIdx.x >> 3;
    const int n = ((blockIdx.x & 7) << 8) + threadIdx.x;
    const double bb = (double)bias[n];
    const PT* p = PSP + (size_t)t * NN + n;     // + b*(50*2048)

    double s = 0.0;
#pragma unroll 8
    for (int b = 0; b < BATCH; ++b) s += (double)p[(size_t)b * (TT * NN)];
    const double mean = s * (1.0 / BATCH) + bb;

    double ss = 0.0;
#pragma unroll 8
    for (int b = 0; b < BATCH; ++b) {
        double d = ((double)p[(size_t)b * (TT * NN)] + bb) - mean;
        ss += d * d;
    }
    const double var = ss * (1.0 / BATCH);
    mean_out[t * NN + n]   = mean;
    invstd_out[t * NN + n] = 1.0 / sqrt(var + BN_EPS);
}

// ---------------------------------------------------------------------------
// LIF recurrence (fp64 state) + coalesced spike writeout via LDS transpose.
// ---------------------------------------------------------------------------
template <typename PT>
__global__ __launch_bounds__(256) void recur_kernel(
    const PT* __restrict__ PSP,           // [M][N]
    const float* __restrict__ bias,       // [N]
    const double* __restrict__ mean_arr,  // [T][N]
    const double* __restrict__ invstd_arr,// [T][N]
    const float* __restrict__ gamma,      // [T][N]
    const float* __restrict__ decay_v,    // [N]
    const float* __restrict__ reset_decay,// [N]
    const float* __restrict__ reset_v,    // [N]
    float* __restrict__ out)              // spikes [B][N][T] ++ final_v ++ final_reset
{
    __shared__ float spk[256 * (TT + 1)];

    const int b  = blockIdx.x >> 3;
    const int nc = blockIdx.x & 7;
    const int n  = (nc << 8) + threadIdx.x;
    const int tid = threadIdx.x;

    const double dv = (double)decay_v[n];
    const double rd = (double)reset_decay[n];
    const double rv = (double)reset_v[n];
    const double bb = (double)bias[n];

    double v = 0.0, r = 0.0;
    const PT* p = PSP + (size_t)b * (TT * NN) + n;   // + t*NN
    const float* ga = gamma + n;
    const double* me = mean_arr + n;
    const double* is = invstd_arr + n;

    for (int t = 0; t < TT; ++t) {
        const double psp = (double)p[t * NN] + bb;
        const double bn  = (double)ga[t * NN] * (psp - me[t * NN]) * is[t * NN];
        v = v * dv + bn - r;
        const double s = (v > 1.0) ? 1.0 : 0.0;
        r = r * rd + s * rv;
        spk[tid * (TT + 1) + t] = (float)s;
    }
    __syncthreads();

    const size_t base = (size_t)b * (NN * TT) + (size_t)nc * (256 * TT);
    for (int i = tid; i < 256 * TT; i += 256) {
        const int n_l = i / TT;
        const int t   = i - n_l * TT;
        out[base + i] = spk[n_l * (TT + 1) + t];
    }

    const size_t fin = (size_t)BATCH * NN * TT;
    out[fin + (size_t)b * NN + n]                      = (float)v;
    out[fin + (size_t)BATCH * NN + (size_t)b * NN + n] = (float)r;
}

// ---------------------------------------------------------------------------
template <typename PT>
static void launch_all(const float* X, const float* W, const float* bias,
                       const float* gamma, const float* decay_v,
                       const float* reset_dec, const float* reset_v,
                       float* out, void* d_ws, hipStream_t stream)
{
    PT* PSP = (PT*)d_ws;
    char* after = (char*)d_ws + (size_t)MM * NN * sizeof(PT);
    double* meanA  = (double*)after;
    double* invstd = meanA + (size_t)TT * NN;

    // probe scratch = start of PSP region (overwritten by the GEMM next)
    i8_probe_kernel<<<1, 64, 0, stream>>>((double*)d_ws);

    dim3 ggrid(NN / 64, MM / 64);   // (32, 100)
    gemm_psp_kernel<PT><<<ggrid, 256, 0, stream>>>(X, W, PSP);
    stats_kernel<PT><<<TT * (NN / 256), 256, 0, stream>>>(PSP, bias, meanA, invstd);
    recur_kernel<PT><<<BATCH * (NN / 256), 256, 0, stream>>>(
        PSP, bias, meanA, invstd, gamma, decay_v, reset_dec, reset_v, out);
}

extern "C" void kernel_launch(void* const* d_in, const int* in_sizes, int n_in,
                              void* d_out, int out_size, void* d_ws, size_t ws_size,
                              hipStream_t stream) {
    (void)in_sizes; (void)n_in; (void)out_size;
    const float* X          = (const float*)d_in[0];  // [B, DIN, T]
    const float* W          = (const float*)d_in[1];  // [N, DIN]
    const float* bias       = (const float*)d_in[2];  // [N]
    const float* gamma      = (const float*)d_in[3];  // [T, N]
    const float* decay_v    = (const float*)d_in[4];  // [N]
    const float* reset_dec  = (const float*)d_in[5];  // [N]
    const float* reset_v    = (const float*)d_in[6];  // [N]
    float* out = (float*)d_out;

    const size_t need_d = (size_t)MM * NN * 8 + (size_t)TT * NN * 16;
    if (ws_size >= need_d)
        launch_all<double>(X, W, bias, gamma, decay_v, reset_dec, reset_v, out, d_ws, stream);
    else
        launch_all<float>(X, W, bias, gamma, decay_v, reset_dec, reset_v, out, d_ws, stream);
}

// Round 9
// 916.318 us; speedup vs baseline: 1.7929x; 1.1344x over previous
//
#include <hip/hip_runtime.h>
#include <cstddef>
#include <math.h>

// Problem constants (from reference)
#define BATCH 128
#define DIN   2048
#define NN    2048
#define TT    50
#define MM    (BATCH * TT)   // 6400, m = b*50 + t
#define BN_EPS 1e-4
#define NDIG  5

typedef double double4_t __attribute__((ext_vector_type(4)));
typedef int    int4v    __attribute__((ext_vector_type(4)));

// XOR bank swizzle for the fp64 fallback GEMM
#define SWZ(x) (((x) & 7) << 2)

// ===========================================================================
// TIER 1 (ws >= ~193 MB): exact int8-Ozaki GEMM.
// Each fp32 element -> 5 signed 7-bit digits (|d|<=64) vs a per-row 2^e scale.
// psp*sA*sB = sum_w 2^-7w * sum_{i+j=w} Ai.Bj ; 15 pairs (i+j<=4), int32-exact
// (max |acc| = 2048*5*64^2 < 2^26). fp64 recombine + power-of-2 unscale.
// Trajectory error ~3e-10 -> expected spike flips ~0.006.
// i8 MFMA layouts HW-verified (round-8 probe, code 1 = standard):
//   A: m=lane&15, k=(lane>>4)*16+byte | B: n=lane&15, same k
//   D: row=4*(lane>>4)+reg, col=lane&15
// ===========================================================================

// --- split A: X[B][DIN][T] -> Adig[5][M][K] + invA[M] (=2^-eA) -------------
__global__ __launch_bounds__(256) void split_a_kernel(
    const float* __restrict__ X,
    signed char* __restrict__ Adig,
    double* __restrict__ invA)
{
    __shared__ float Xs[64 * TT];     // 64k x 50t tile
    __shared__ float red[4][64];
    __shared__ float sAs[TT];

    const int b = blockIdx.x;
    const int tid = threadIdx.x;
    const float* Xb = X + (size_t)b * (DIN * TT);

    // phase 1: rowmax per t (threads: t = tid&63, k-group = tid>>6)
    const int tl = tid & 63;
    const int kg = tid >> 6;
    float m_loc = 0.f;
    if (tl < TT)
        for (int k = kg; k < DIN; k += 4)
            m_loc = fmaxf(m_loc, fabsf(Xb[k * TT + tl]));
    red[kg][tl] = m_loc;
    __syncthreads();
    if (tid < TT) {
        float m = fmaxf(fmaxf(red[0][tid], red[1][tid]),
                        fmaxf(red[2][tid], red[3][tid]));
        if (m == 0.f) m = 1.f;
        int ex; frexpf(m, &ex);               // m = f*2^ex, f in [0.5,1)
        sAs[tid] = exp2f((float)(6 - ex));    // rowmax*sA in [32,64)
        invA[(size_t)b * TT + tid] = ldexp(1.0, ex - 6);
    }
    __syncthreads();

    // phase 2: digit split + LDS transpose for coalesced byte writes
    for (int k0 = 0; k0 < DIN; k0 += 64) {
        for (int idx = tid; idx < 64 * TT; idx += 256)
            Xs[idx] = Xb[k0 * TT + idx];      // flat-coalesced
        __syncthreads();
        const int kl = tid & 63;
        for (int t = (tid >> 6); t < TT; t += 4) {
            float r = Xs[kl * TT + t] * sAs[t];
            const size_t mrow = (size_t)b * TT + t;
            signed char d[NDIG];
#pragma unroll
            for (int i = 0; i < NDIG; ++i) {
                float di = rintf(r);
                r = (r - di) * 128.f;         // exact in fp32
                d[i] = (signed char)(int)di;  // |di| <= 64
            }
#pragma unroll
            for (int i = 0; i < NDIG; ++i)
                Adig[((size_t)i * MM + mrow) * DIN + k0 + kl] = d[i];
        }
        __syncthreads();
    }
}

// --- split B: W[N][K] -> Bdig[5][N][K] + invB[N] ---------------------------
__global__ __launch_bounds__(256) void split_b_kernel(
    const float* __restrict__ W,
    signed char* __restrict__ Bdig,
    double* __restrict__ invB)
{
    __shared__ float red[256];
    __shared__ float sBsh;
    const int tid = threadIdx.x;
    for (int rep = 0; rep < 4; ++rep) {
        const int n = blockIdx.x * 4 + rep;
        const float* Wr = W + (size_t)n * DIN;
        float m_loc = 0.f;
        for (int k = tid; k < DIN; k += 256)
            m_loc = fmaxf(m_loc, fabsf(Wr[k]));
        red[tid] = m_loc;
        __syncthreads();
        for (int s = 128; s > 0; s >>= 1) {
            if (tid < s) red[tid] = fmaxf(red[tid], red[tid + s]);
            __syncthreads();
        }
        if (tid == 0) {
            float m = (red[0] == 0.f) ? 1.f : red[0];
            int ex; frexpf(m, &ex);
            sBsh = exp2f((float)(6 - ex));
            invB[n] = ldexp(1.0, ex - 6);
        }
        __syncthreads();
        const float sB = sBsh;
        for (int k = tid; k < DIN; k += 256) {
            float r = Wr[k] * sB;
#pragma unroll
            for (int i = 0; i < NDIG; ++i) {
                float di = rintf(r);
                r = (r - di) * 128.f;
                Bdig[((size_t)i * NN + n) * DIN + k] = (signed char)(int)di;
            }
        }
        __syncthreads();
    }
}

// --- i8 GEMM: 64x64 block tile, 4 waves 2x2 (wave 32x32), K-tile 64 --------
__global__ __launch_bounds__(256, 2) void gemm_i8_kernel(
    const signed char* __restrict__ Adig,   // [5][MM][DIN]
    const signed char* __restrict__ Bdig,   // [5][NN][DIN]
    const double* __restrict__ invA,        // [MM]
    const double* __restrict__ invB,        // [NN]
    double* __restrict__ PSP)               // [MM][NN]
{
    __shared__ __align__(16) signed char Asd[NDIG][64][64];
    __shared__ __align__(16) signed char Bsd[NDIG][64][64];

    const int tid = threadIdx.x;
    const int m0 = blockIdx.x * 64;   // 100 (x-fastest: consecutive blocks share B strip)
    const int n0 = blockIdx.y * 64;   // 32

    const int s_row = tid >> 2;
    const int s_k   = (tid & 3) * 16;

    const int lane = tid & 63;
    const int wv   = tid >> 6;
    const int wm   = (wv >> 1) * 32;
    const int wn   = (wv & 1) * 32;
    const int row  = lane & 15;
    const int grp  = lane >> 4;

    int4v acc[NDIG][2][2];
#pragma unroll
    for (int w = 0; w < NDIG; ++w)
#pragma unroll
        for (int i = 0; i < 2; ++i)
#pragma unroll
            for (int j = 0; j < 2; ++j) acc[w][i][j] = int4v{0, 0, 0, 0};

    for (int k0 = 0; k0 < DIN; k0 += 64) {
        __syncthreads();   // previous iter's frag reads complete
#pragma unroll
        for (int p = 0; p < NDIG; ++p) {
            *(int4*)&Asd[p][s_row][s_k] =
                *(const int4*)&Adig[((size_t)p * MM + m0 + s_row) * DIN + k0 + s_k];
            *(int4*)&Bsd[p][s_row][s_k] =
                *(const int4*)&Bdig[((size_t)p * NN + n0 + s_row) * DIN + k0 + s_k];
        }
        __syncthreads();

        int4v aF[NDIG][2];
#pragma unroll
        for (int i = 0; i < NDIG; ++i) {
            aF[i][0] = *(const int4v*)&Asd[i][wm + row][grp * 16];
            aF[i][1] = *(const int4v*)&Asd[i][wm + row + 16][grp * 16];
        }
#pragma unroll
        for (int j = 0; j < NDIG; ++j) {
            const int4v bF0 = *(const int4v*)&Bsd[j][wn + row][grp * 16];
            const int4v bF1 = *(const int4v*)&Bsd[j][wn + row + 16][grp * 16];
#pragma unroll
            for (int i = 0; i + j < NDIG; ++i) {
                const int w = i + j;
                acc[w][0][0] = __builtin_amdgcn_mfma_i32_16x16x64_i8(aF[i][0], bF0, acc[w][0][0], 0, 0, 0);
                acc[w][0][1] = __builtin_amdgcn_mfma_i32_16x16x64_i8(aF[i][0], bF1, acc[w][0][1], 0, 0, 0);
                acc[w][1][0] = __builtin_amdgcn_mfma_i32_16x16x64_i8(aF[i][1], bF0, acc[w][1][0], 0, 0, 0);
                acc[w][1][1] = __builtin_amdgcn_mfma_i32_16x16x64_i8(aF[i][1], bF1, acc[w][1][1], 0, 0, 0);
            }
        }
    }

    // epilogue: D standard layout (probe code 1): row=4*grp+r, col=lane&15
    const double c1 = 1.0 / 128.0, c2 = c1 * c1, c3 = c2 * c1, c4 = c2 * c2;
#pragma unroll
    for (int ih = 0; ih < 2; ++ih)
#pragma unroll
        for (int jh = 0; jh < 2; ++jh) {
            const int ncol = n0 + wn + 16 * jh + row;
            const double ib = invB[ncol];
#pragma unroll
            for (int r = 0; r < 4; ++r) {
                const int mrow = m0 + wm + 16 * ih + 4 * grp + r;
                double s = (double)acc[0][ih][jh][r]
                         + c1 * (double)acc[1][ih][jh][r]
                         + c2 * (double)acc[2][ih][jh][r]
                         + c3 * (double)acc[3][ih][jh][r]
                         + c4 * (double)acc[4][ih][jh][r];
                PSP[(size_t)mrow * NN + ncol] = s * invA[mrow] * ib;
            }
        }
}

// ===========================================================================
// TIER 2 fallback: fp64-MFMA GEMM (round-8, proven 1039 us total)
// ===========================================================================
#define BKK 32

template <typename PT>
__global__ __launch_bounds__(256, 5) void gemm_psp_kernel(
    const float* __restrict__ X,
    const float* __restrict__ W,
    PT* __restrict__ PSP)
{
    __shared__ float As[2][BKK][64];
    __shared__ float Bs[2][64][BKK];

    const int tid = threadIdx.x;
    const int m0 = blockIdx.y * 64;
    const int n0 = blockIdx.x * 64;

    const int a_m = tid & 63;
    const int a_k = tid >> 6;
    const int m_g = m0 + a_m;
    const int ab  = m_g / TT;
    const int at  = m_g - ab * TT;
    const float* Aptr = X + (size_t)ab * (DIN * TT) + at;

    const int b_n = tid >> 2;
    const int b_k = (tid & 3) * 8;
    const float* Wptr = W + (size_t)(n0 + b_n) * DIN + b_k;
    const int bswz_st = SWZ(b_n);

    const int lane = tid & 63;
    const int wv   = tid >> 6;
    const int wm   = (wv >> 1) * 32;
    const int wn   = (wv & 1) * 32;
    const int row  = lane & 15;
    const int grp  = lane >> 4;
    const int bswz_rd = SWZ(row);

    double4_t acc[2][2];
#pragma unroll
    for (int i = 0; i < 2; ++i)
#pragma unroll
        for (int j = 0; j < 2; ++j) acc[i][j] = double4_t{0.0, 0.0, 0.0, 0.0};

    {
#pragma unroll
        for (int j = 0; j < 8; ++j) {
            const int kr = a_k + 4 * j;
            As[0][kr][a_m ^ SWZ(kr)] = Aptr[kr * TT];
        }
        *(float4*)&Bs[0][b_n][(b_k + 0) ^ bswz_st] = *(const float4*)(Wptr);
        *(float4*)&Bs[0][b_n][(b_k + 4) ^ bswz_st] = *(const float4*)(Wptr + 4);
    }

    const int NIT = DIN / BKK;
    for (int it = 0; it < NIT; ++it) {
        const int buf = it & 1;
        __syncthreads();

        float a_nxt[8];
        float4 b_nxt0, b_nxt1;
        if (it + 1 < NIT) {
            const int k0n = (it + 1) * BKK;
#pragma unroll
            for (int j = 0; j < 8; ++j)
                a_nxt[j] = Aptr[(k0n + a_k + 4 * j) * TT];
            b_nxt0 = *(const float4*)(Wptr + k0n);
            b_nxt1 = *(const float4*)(Wptr + k0n + 4);
        }

#pragma unroll
        for (int kq = 0; kq < BKK; kq += 4) {
            const int kr = kq + grp;
            const int aswz = SWZ(kr);
            const double a0 = (double)As[buf][kr][(wm + row) ^ aswz];
            const double a1 = (double)As[buf][kr][(wm + row + 16) ^ aswz];
            const double b0 = (double)Bs[buf][wn + row][kr ^ bswz_rd];
            const double b1 = (double)Bs[buf][wn + row + 16][kr ^ bswz_rd];
            acc[0][0] = __builtin_amdgcn_mfma_f64_16x16x4f64(a0, b0, acc[0][0], 0, 0, 0);
            acc[0][1] = __builtin_amdgcn_mfma_f64_16x16x4f64(a0, b1, acc[0][1], 0, 0, 0);
            acc[1][0] = __builtin_amdgcn_mfma_f64_16x16x4f64(a1, b0, acc[1][0], 0, 0, 0);
            acc[1][1] = __builtin_amdgcn_mfma_f64_16x16x4f64(a1, b1, acc[1][1], 0, 0, 0);
        }

        if (it + 1 < NIT) {
            const int nb = 1 - buf;
#pragma unroll
            for (int j = 0; j < 8; ++j) {
                const int kr = a_k + 4 * j;
                As[nb][kr][a_m ^ SWZ(kr)] = a_nxt[j];
            }
            *(float4*)&Bs[nb][b_n][(b_k + 0) ^ bswz_st] = b_nxt0;
            *(float4*)&Bs[nb][b_n][(b_k + 4) ^ bswz_st] = b_nxt1;
        }
    }

#pragma unroll
    for (int i = 0; i < 2; ++i)
#pragma unroll
        for (int j = 0; j < 2; ++j)
#pragma unroll
            for (int r = 0; r < 4; ++r) {
                const int mrow = m0 + wm + 16 * i + grp + 4 * r;   // f64 H2 layout
                PSP[(size_t)mrow * NN + (n0 + wn + 16 * j + row)] = (PT)acc[i][j][r];
            }
}

// ---------------------------------------------------------------------------
// BN stats + LIF recurrence (shared by all tiers)
// ---------------------------------------------------------------------------
template <typename PT>
__global__ __launch_bounds__(256) void stats_kernel(
    const PT* __restrict__ PSP, const float* __restrict__ bias,
    double* __restrict__ mean_out, double* __restrict__ invstd_out)
{
    const int t = blockIdx.x >> 3;
    const int n = ((blockIdx.x & 7) << 8) + threadIdx.x;
    const double bb = (double)bias[n];
    const PT* p = PSP + (size_t)t * NN + n;

    double s = 0.0;
#pragma unroll 8
    for (int b = 0; b < BATCH; ++b) s += (double)p[(size_t)b * (TT * NN)];
    const double mean = s * (1.0 / BATCH) + bb;

    double ss = 0.0;
#pragma unroll 8
    for (int b = 0; b < BATCH; ++b) {
        double d = ((double)p[(size_t)b * (TT * NN)] + bb) - mean;
        ss += d * d;
    }
    mean_out[t * NN + n]   = mean;
    invstd_out[t * NN + n] = 1.0 / sqrt(ss * (1.0 / BATCH) + BN_EPS);
}

template <typename PT>
__global__ __launch_bounds__(256) void recur_kernel(
    const PT* __restrict__ PSP, const float* __restrict__ bias,
    const double* __restrict__ mean_arr, const double* __restrict__ invstd_arr,
    const float* __restrict__ gamma, const float* __restrict__ decay_v,
    const float* __restrict__ reset_decay, const float* __restrict__ reset_v,
    float* __restrict__ out)
{
    __shared__ float spk[256 * (TT + 1)];

    const int b  = blockIdx.x >> 3;
    const int nc = blockIdx.x & 7;
    const int n  = (nc << 8) + threadIdx.x;
    const int tid = threadIdx.x;

    const double dv = (double)decay_v[n];
    const double rd = (double)reset_decay[n];
    const double rv = (double)reset_v[n];
    const double bb = (double)bias[n];

    double v = 0.0, r = 0.0;
    const PT* p = PSP + (size_t)b * (TT * NN) + n;
    const float* ga = gamma + n;
    const double* me = mean_arr + n;
    const double* is = invstd_arr + n;

    for (int t = 0; t < TT; ++t) {
        const double psp = (double)p[t * NN] + bb;
        const double bn  = (double)ga[t * NN] * (psp - me[t * NN]) * is[t * NN];
        v = v * dv + bn - r;
        const double s = (v > 1.0) ? 1.0 : 0.0;
        r = r * rd + s * rv;
        spk[tid * (TT + 1) + t] = (float)s;
    }
    __syncthreads();

    const size_t base = (size_t)b * (NN * TT) + (size_t)nc * (256 * TT);
    for (int i = tid; i < 256 * TT; i += 256) {
        const int n_l = i / TT;
        out[base + i] = spk[n_l * (TT + 1) + (i - n_l * TT)];
    }

    const size_t fin = (size_t)BATCH * NN * TT;
    out[fin + (size_t)b * NN + n]                      = (float)v;
    out[fin + (size_t)BATCH * NN + (size_t)b * NN + n] = (float)r;
}

// ---------------------------------------------------------------------------
template <typename PT>
static void launch_fp64(const float* X, const float* W, const float* bias,
                        const float* gamma, const float* decay_v,
                        const float* reset_dec, const float* reset_v,
                        float* out, void* d_ws, hipStream_t stream)
{
    PT* PSP = (PT*)d_ws;
    char* after = (char*)d_ws + (size_t)MM * NN * sizeof(PT);
    double* meanA  = (double*)after;
    double* invstd = meanA + (size_t)TT * NN;

    dim3 ggrid(NN / 64, MM / 64);
    gemm_psp_kernel<PT><<<ggrid, 256, 0, stream>>>(X, W, PSP);
    stats_kernel<PT><<<TT * (NN / 256), 256, 0, stream>>>(PSP, bias, meanA, invstd);
    recur_kernel<PT><<<BATCH * (NN / 256), 256, 0, stream>>>(
        PSP, bias, meanA, invstd, gamma, decay_v, reset_dec, reset_v, out);
}

extern "C" void kernel_launch(void* const* d_in, const int* in_sizes, int n_in,
                              void* d_out, int out_size, void* d_ws, size_t ws_size,
                              hipStream_t stream) {
    (void)in_sizes; (void)n_in; (void)out_size;
    const float* X          = (const float*)d_in[0];
    const float* W          = (const float*)d_in[1];
    const float* bias       = (const float*)d_in[2];
    const float* gamma      = (const float*)d_in[3];
    const float* decay_v    = (const float*)d_in[4];
    const float* reset_dec  = (const float*)d_in[5];
    const float* reset_v    = (const float*)d_in[6];
    float* out = (float*)d_out;

    const size_t psp_d   = (size_t)MM * NN * sizeof(double);   // 104.86 MB
    const size_t stats_b = (size_t)TT * NN * 2 * sizeof(double);
    const size_t adig_b  = (size_t)NDIG * MM * DIN;            // 65.54 MB
    const size_t bdig_b  = (size_t)NDIG * NN * DIN;            // 20.97 MB
    const size_t need_i8 = psp_d + stats_b + adig_b + bdig_b + (MM + NN) * sizeof(double);
    const size_t need_d  = psp_d + stats_b;

    if (ws_size >= need_i8) {
        double* PSP    = (double*)d_ws;
        char*   cur    = (char*)d_ws + psp_d;
        double* meanA  = (double*)cur;              cur += (size_t)TT * NN * 8;
        double* invstd = (double*)cur;              cur += (size_t)TT * NN * 8;
        signed char* Adig = (signed char*)cur;      cur += adig_b;
        signed char* Bdig = (signed char*)cur;      cur += bdig_b;
        double* invA   = (double*)cur;              cur += (size_t)MM * 8;
        double* invB   = (double*)cur;

        split_a_kernel<<<BATCH, 256, 0, stream>>>(X, Adig, invA);
        split_b_kernel<<<NN / 4, 256, 0, stream>>>(W, Bdig, invB);
        gemm_i8_kernel<<<dim3(MM / 64, NN / 64), 256, 0, stream>>>(
            Adig, Bdig, invA, invB, PSP);
        stats_kernel<double><<<TT * (NN / 256), 256, 0, stream>>>(PSP, bias, meanA, invstd);
        recur_kernel<double><<<BATCH * (NN / 256), 256, 0, stream>>>(
            PSP, bias, meanA, invstd, gamma, decay_v, reset_dec, reset_v, out);
    } else if (ws_size >= need_d) {
        launch_fp64<double>(X, W, bias, gamma, decay_v, reset_dec, reset_v, out, d_ws, stream);
    } else {
        launch_fp64<float>(X, W, bias, gamma, decay_v, reset_dec, reset_v, out, d_ws, stream);
    }
}